// Round 7
// baseline (71.721 us; speedup 1.0000x reference)
//
#include <hip/hip_runtime.h>

// Problem constants (fixed by setup_inputs)
#define T_DIM 32
#define B_DIM 64
#define D_DIM 256
#define P_DIM 1024
#define NK    17
#define DT    0.1875f    // 3/16

#define KC    128        // K-chunk for the MFMA tiles
#define LROW  136        // padded LDS row (128+8 bf16) = 272 B

typedef __bf16 bf16x8 __attribute__((ext_vector_type(8)));
typedef float  f32x4  __attribute__((ext_vector_type(4)));

static __device__ __forceinline__ unsigned f2bf(float f) {
  unsigned u = __float_as_uint(f);
  u += 0x7fffu + ((u >> 16) & 1u);     // round-to-nearest-even
  return u >> 16;
}

// ---------------------------------------------------------------------------
// Single fused kernel. grid (16 ptile, 32 t) x 512 thr (8 waves -> 4/SIMD,
// double round-6's occupancy; per-thread work halves).
// Wave wv = (mq = wv>>1: b-quarter of 16, nh = wv&1: p-half of 32).
// Each wave: 16x16x32 bf16 MFMA, 2 N-tiles, full K=256 (8 k-steps x 2) ->
// each lane holds 8 x values (4 b x 2 p). Then Chebyshev cos/sin sums,
// quad-shuffle combine, LDS planes, weighted error, one atomicAdd per block.
// LDS 43264 B: bf16 tiles proj[64][136] + A^T[64][136] (34816 B, reused for
// the reduction planes) + normred[32][64] + invn[64].
// ---------------------------------------------------------------------------
__global__ __launch_bounds__(512, 4) void sig_fused_kernel(const float* __restrict__ proj,
                                                           const float* __restrict__ A,
                                                           float* __restrict__ out) {
  __shared__ float smf[10816];                   // 43264 B
  unsigned short* sp = (unsigned short*)smf;     // proj tile [b][k]
  unsigned short* sa = sp + 64 * LROW;           // A^T tile  [p][k]
  float* normred = smf + 8704;                   // [32 dgq][64 p]
  float* invn    = smf + 10752;                  // [64]

  const int tid  = threadIdx.x;
  const int lane = tid & 63;
  const int wv   = tid >> 6;                     // 0..7
  const int mq   = wv >> 1;                      // b-quarter (16 b)
  const int nh   = wv & 1;                       // p-half (32 p)
  const int p0   = blockIdx.x * 64;
  const int t    = blockIdx.y;

  const float4* Pg = (const float4*)(proj + (size_t)t * B_DIM * D_DIM);
  const float4* Ag = (const float4*)(A + p0);    // row stride P_DIM/4 float4

  const int pg  = tid & 15;                      // A-stage float4 col (4 p's)
  const int dgq = tid >> 4;                      // 0..31, 4 d's each per chunk

  const int l15 = lane & 15;
  const int mrow  = mq * 16 + l15;               // A-frag b row
  const int prow0 = nh * 32 + l15;               // B-frag p rows (2 N-tiles)
  const int prow1 = prow0 + 16;
  const int kq    = (lane >> 4) * 8;             // frag k sub-offset

  f32x4 acc0 = {0.f, 0.f, 0.f, 0.f};
  f32x4 acc1 = {0.f, 0.f, 0.f, 0.f};
  float nrm[4] = {0.f, 0.f, 0.f, 0.f};

#pragma unroll
  for (int c = 0; c < 2; ++c) {
    const int kc = c * KC;
    // ---- stage proj chunk: 1024 uint4, 2 per thread, fp32 -> bf16 ----
#pragma unroll
    for (int r = 0; r < 2; ++r) {
      int idx = tid + r * 512;                   // 0..1023
      int row = idx >> 4, cp = idx & 15;
      float4 v0 = Pg[row * 64 + kc / 4 + cp * 2];
      float4 v1 = Pg[row * 64 + kc / 4 + cp * 2 + 1];
      uint4 w;
      w.x = f2bf(v0.x) | (f2bf(v0.y) << 16);
      w.y = f2bf(v0.z) | (f2bf(v0.w) << 16);
      w.z = f2bf(v1.x) | (f2bf(v1.y) << 16);
      w.w = f2bf(v1.z) | (f2bf(v1.w) << 16);
      *(uint4*)&sp[row * LROW + cp * 8] = w;
    }
    // ---- stage A chunk transposed: thread owns 4 p-cols x 4 d's ----
    {
      float4 va[4];
#pragma unroll
      for (int i = 0; i < 4; ++i)
        va[i] = Ag[(size_t)(kc + dgq * 4 + i) * (P_DIM / 4) + pg];
#pragma unroll
      for (int j = 0; j < 4; ++j) {
        float e0 = ((const float*)&va[0])[j];
        float e1 = ((const float*)&va[1])[j];
        float e2 = ((const float*)&va[2])[j];
        float e3 = ((const float*)&va[3])[j];
        nrm[j] = fmaf(e0, e0, nrm[j]); nrm[j] = fmaf(e1, e1, nrm[j]);
        nrm[j] = fmaf(e2, e2, nrm[j]); nrm[j] = fmaf(e3, e3, nrm[j]);
        uint2 w;
        w.x = f2bf(e0) | (f2bf(e1) << 16);
        w.y = f2bf(e2) | (f2bf(e3) << 16);
        *(uint2*)&sa[(pg * 4 + j) * LROW + dgq * 4] = w;
      }
    }
    if (c == 1) {                                // norms complete after chunk 1
#pragma unroll
      for (int j = 0; j < 4; ++j) normred[dgq * 64 + pg * 4 + j] = nrm[j];
    }
    __syncthreads();

    // ---- MFMA over this chunk: 4 k-steps x 2 N-tiles ----
#pragma unroll
    for (int ks = 0; ks < 4; ++ks) {
      int kb = ks * 32 + kq;
      bf16x8 af = *(const bf16x8*)&sp[mrow * LROW + kb];
      bf16x8 b0 = *(const bf16x8*)&sa[prow0 * LROW + kb];
      bf16x8 b1 = *(const bf16x8*)&sa[prow1 * LROW + kb];
      acc0 = __builtin_amdgcn_mfma_f32_16x16x32_bf16(af, b0, acc0, 0, 0, 0);
      acc1 = __builtin_amdgcn_mfma_f32_16x16x32_bf16(af, b1, acc1, 0, 0, 0);
    }
    __syncthreads();                             // frag reads done before restage/reuse
  }
  // acc_nt[r] = x_unnorm[b = mq*16 + (lane>>4)*4 + r][p = nh*32 + nt*16 + l15]

  // ---- finish column norms -> invn[p] ----
  if (tid < 64) {
    float s = 0.f;
#pragma unroll
    for (int q = 0; q < 32; ++q) s += normred[q * 64 + tid];
    invn[tid] = rsqrtf(fmaxf(s, 1e-24f));        // 1/clamp_min(norm, 1e-12)
  }
  __syncthreads();

  // ---- trig + plane writes, one N-tile at a time (keeps VGPRs < 128) ----
  // planes (reuse tile LDS): cos[k<16][mq<4][p<64] @0, sin @4096
#pragma unroll
  for (int nt = 0; nt < 2; ++nt) {
    const f32x4 a = nt ? acc1 : acc0;
    const int   p = nh * 32 + nt * 16 + l15;
    const float invdt = invn[p] * DT;
    float cs[NK - 1], ss[NK - 1];
#pragma unroll
    for (int k = 0; k < NK - 1; ++k) { cs[k] = 0.f; ss[k] = 0.f; }
#pragma unroll
    for (int r = 0; r < 4; ++r) {
      float th = a[r] * invdt;
      float s1, c1;
      __sincosf(th, &s1, &c1);
      float twoc = 2.f * c1;
      float ckm1 = 1.f, skm1 = 0.f;
      float ck = c1, sk = s1;
      cs[0] += c1;
      ss[0] += s1;
#pragma unroll
      for (int k = 2; k < NK; ++k) {
        float cn = fmaf(twoc, ck, -ckm1);
        float sn = fmaf(twoc, sk, -skm1);
        cs[k - 1] += cn;
        ss[k - 1] += sn;
        ckm1 = ck; skm1 = sk; ck = cn; sk = sn;
      }
    }
    // combine the 4 b-quads of this wave (lanes L, L^16, L^32, L^48 share p)
#pragma unroll
    for (int k = 0; k < NK - 1; ++k) {
      cs[k] += __shfl_xor(cs[k], 16, 64);
      cs[k] += __shfl_xor(cs[k], 32, 64);
      ss[k] += __shfl_xor(ss[k], 16, 64);
      ss[k] += __shfl_xor(ss[k], 32, 64);
    }
    if (lane < 16) {
#pragma unroll
      for (int k = 0; k < NK - 1; ++k) {
        smf[k * 256 + mq * 64 + p]        = cs[k];
        smf[4096 + k * 256 + mq * 64 + p] = ss[k];
      }
    }
  }
  __syncthreads();

  // ---- per-(k,p) error + weight dot: 1024 entries over 512 threads ----
  float part = 0.f;
#pragma unroll
  for (int r = 0; r < 2; ++r) {
    int e  = tid + r * 512;                      // 0..1023
    int k1 = e >> 6;
    int pl = e & 63;
    float C = 0.f, S = 0.f;
#pragma unroll
    for (int m = 0; m < 4; ++m) {
      C += smf[k1 * 256 + m * 64 + pl];
      S += smf[4096 + k1 * 256 + m * 64 + pl];
    }
    float cm  = C * (1.f / 64.f);
    float sm_ = S * (1.f / 64.f);
    float tk  = (float)(k1 + 1) * DT;
    float phi = __expf(-0.5f * tk * tk);
    float wk  = ((k1 == NK - 2) ? DT : 2.f * DT) * phi;   // k=16 endpoint
    float dc  = cm - phi;
    part = fmaf(wk, fmaf(dc, dc, sm_ * sm_), part);
  }
  part *= (1.f / 512.f);                         // * B / (T*P)

  // ---- block reduce -> one atomic per block ----
#pragma unroll
  for (int off = 32; off > 0; off >>= 1)
    part += __shfl_down(part, off, 64);
  if (lane == 0) smf[8192 + wv] = part;          // disjoint from planes (<8192)
  __syncthreads();
  if (tid == 0) {
    float s = 0.f;
#pragma unroll
    for (int w = 0; w < 8; ++w) s += smf[8192 + w];
    atomicAdd(out, s);
  }
}

// ---------------------------------------------------------------------------
extern "C" void kernel_launch(void* const* d_in, const int* in_sizes, int n_in,
                              void* d_out, int out_size, void* d_ws, size_t ws_size,
                              hipStream_t stream) {
  const float* proj = (const float*)d_in[0];     // (32,64,256) fp32
  const float* A    = (const float*)d_in[1];     // (256,1024) fp32
  float* out        = (float*)d_out;             // 1 fp32 scalar

  hipMemsetAsync(out, 0, sizeof(float), stream); // d_out poisoned each call
  sig_fused_kernel<<<dim3(16, 32), dim3(512), 0, stream>>>(proj, A, out);
}

// Round 8
// 69.956 us; speedup vs baseline: 1.0252x; 1.0252x over previous
//
#include <hip/hip_runtime.h>

// Problem constants (fixed by setup_inputs)
#define T_DIM 32
#define B_DIM 64
#define D_DIM 256
#define P_DIM 1024
#define NK    17
#define DT    0.1875f    // 3/16
#define DT_REV 0.029841551329651566f   // DT / (2*pi) -- v_sin/v_cos take revolutions

#define KC    128        // K-chunk for the MFMA tiles
#define LROW  136        // padded LDS row (128+8 bf16) = 272 B

typedef __bf16 bf16x8 __attribute__((ext_vector_type(8)));
typedef float  f32x16 __attribute__((ext_vector_type(16)));

static __device__ __forceinline__ unsigned f2bf(float f) {
  unsigned u = __float_as_uint(f);
  u += 0x7fffu + ((u >> 16) & 1u);     // round-to-nearest-even
  return u >> 16;
}

// ---------------------------------------------------------------------------
// Single fused kernel. grid (16 ptile, 32 t) x 256 thr (4 waves).
//  - stages proj (fp32->bf16) and A (fp32->bf16, transposed to [p][d]) into
//    LDS per 128-wide K chunk; A column sum-of-squares accumulated during
//    staging (norm applied to acc AFTER the GEMM -- it's linear)
//  - X = proj @ A via 32x32x16 bf16 MFMA, one 32x32 tile per wave
//  - HW trig (v_sin/v_cos, revolutions) + Chebyshev recurrence for the 16
//    harmonics; cos/sin sums over B; weighted error; one atomicAdd per block
// LDS: 2 bf16 tiles [64][136] (34816 B) + normred[16][64] + invn[64]
//      = 39168 B.
// ---------------------------------------------------------------------------
__global__ __launch_bounds__(256) void sig_fused_kernel(const float* __restrict__ proj,
                                                        const float* __restrict__ A,
                                                        float* __restrict__ out) {
  __shared__ float smf[9792];                    // 39168 B
  unsigned short* sp = (unsigned short*)smf;     // proj tile [b][k], padded
  unsigned short* sa = sp + 64 * LROW;           // A^T tile  [p][k], padded
  float* normred = smf + 8704;                   // [16 dg][64 p]
  float* invn    = smf + 9728;                   // [64]

  const int tid  = threadIdx.x;
  const int lane = tid & 63;
  const int wv   = tid >> 6;                     // 0..3
  const int p0   = blockIdx.x * 64;
  const int t    = blockIdx.y;

  const int mt = wv >> 1, nt = wv & 1;
  const int mrow = mt * 32 + (lane & 31);        // b row of this lane's A-frag
  const int nrow = nt * 32 + (lane & 31);        // p row of this lane's B-frag
  const int koff = (lane >> 5) * 8;

  const float4* Pg = (const float4*)(proj + (size_t)t * B_DIM * D_DIM);
  const float4* Ag = (const float4*)(A + p0);    // row stride P_DIM/4 float4

  const int pg = tid & 15;                       // p-group (4 p's)
  const int dg = tid >> 4;                       // 0..15, 8 d's each

  f32x16 acc = {0.f, 0.f, 0.f, 0.f, 0.f, 0.f, 0.f, 0.f,
                0.f, 0.f, 0.f, 0.f, 0.f, 0.f, 0.f, 0.f};
  float nrm[4] = {0.f, 0.f, 0.f, 0.f};

  for (int kc = 0; kc < D_DIM; kc += KC) {
    // ---- stage proj chunk: 4 row-pairs per thread, fp32 -> bf16 ----
#pragma unroll
    for (int r = 0; r < 4; ++r) {
      int pair = tid + r * 256;                  // 0..1023
      int row = pair >> 4, cp = pair & 15;       // 16 8-wide k-groups per row
      float4 v0 = Pg[row * 64 + kc / 4 + cp * 2];
      float4 v1 = Pg[row * 64 + kc / 4 + cp * 2 + 1];
      uint4 w;
      w.x = f2bf(v0.x) | (f2bf(v0.y) << 16);
      w.y = f2bf(v0.z) | (f2bf(v0.w) << 16);
      w.z = f2bf(v1.x) | (f2bf(v1.y) << 16);
      w.w = f2bf(v1.z) | (f2bf(v1.w) << 16);
      *(uint4*)&sp[row * LROW + cp * 8] = w;
    }
    // ---- stage A chunk transposed: thread owns 4 p-cols x 8 d's ----
    {
      float4 va[8];
#pragma unroll
      for (int i = 0; i < 8; ++i)
        va[i] = Ag[(size_t)(kc + dg * 8 + i) * (P_DIM / 4) + pg];
#pragma unroll
      for (int j = 0; j < 4; ++j) {
        float e0 = ((const float*)&va[0])[j], e1 = ((const float*)&va[1])[j];
        float e2 = ((const float*)&va[2])[j], e3 = ((const float*)&va[3])[j];
        float e4 = ((const float*)&va[4])[j], e5 = ((const float*)&va[5])[j];
        float e6 = ((const float*)&va[6])[j], e7 = ((const float*)&va[7])[j];
        nrm[j] = fmaf(e0, e0, nrm[j]); nrm[j] = fmaf(e1, e1, nrm[j]);
        nrm[j] = fmaf(e2, e2, nrm[j]); nrm[j] = fmaf(e3, e3, nrm[j]);
        nrm[j] = fmaf(e4, e4, nrm[j]); nrm[j] = fmaf(e5, e5, nrm[j]);
        nrm[j] = fmaf(e6, e6, nrm[j]); nrm[j] = fmaf(e7, e7, nrm[j]);
        uint4 w;
        w.x = f2bf(e0) | (f2bf(e1) << 16);
        w.y = f2bf(e2) | (f2bf(e3) << 16);
        w.z = f2bf(e4) | (f2bf(e5) << 16);
        w.w = f2bf(e6) | (f2bf(e7) << 16);
        *(uint4*)&sa[(pg * 4 + j) * LROW + dg * 8] = w;
      }
    }
    if (kc != 0) {                               // norms complete on last chunk
#pragma unroll
      for (int j = 0; j < 4; ++j) normred[dg * 64 + pg * 4 + j] = nrm[j];
    }
    __syncthreads();

    // ---- MFMA over this chunk: 8 k-steps ----
#pragma unroll
    for (int ks = 0; ks < 8; ++ks) {
      int k = ks * 16 + koff;
      bf16x8 af = *(const bf16x8*)&sp[mrow * LROW + k];
      bf16x8 bf = *(const bf16x8*)&sa[nrow * LROW + k];
      acc = __builtin_amdgcn_mfma_f32_32x32x16_bf16(af, bf, acc, 0, 0, 0);
    }
    __syncthreads();                             // frag reads done before restage/reuse
  }
  // acc reg r = x_unnorm[b = mt*32+(r&3)+8*(r>>2)+4*(lane>>5)][p = nt*32+(lane&31)]

  // ---- finish column norms -> invn[p] ----
  if (tid < 64) {
    float s = 0.f;
#pragma unroll
    for (int q = 0; q < 16; ++q) s += normred[q * 64 + tid];
    invn[tid] = rsqrtf(fmaxf(s, 1e-24f));        // 1/clamp_min(norm, 1e-12)
  }
  __syncthreads();
  // scale to REVOLUTIONS: theta = x*DT, hw trig wants theta/2pi
  const float invdt = invn[nt * 32 + (lane & 31)] * DT_REV;

  // ---- Chebyshev trig via HW v_sin/v_cos: sums over this lane's 16 b's ----
  float cs[NK - 1], ss[NK - 1];
#pragma unroll
  for (int k = 0; k < NK - 1; ++k) { cs[k] = 0.f; ss[k] = 0.f; }
#pragma unroll
  for (int r = 0; r < 16; ++r) {
    float th = acc[r] * invdt;                   // revolutions, |th| << 1
    float c1 = __builtin_amdgcn_cosf(th);        // v_cos_f32: cos(2*pi*th)
    float s1 = __builtin_amdgcn_sinf(th);        // v_sin_f32: sin(2*pi*th)
    float twoc = 2.f * c1;
    float ckm1 = 1.f, skm1 = 0.f;
    float ck = c1, sk = s1;
    cs[0] += c1;
    ss[0] += s1;
#pragma unroll
    for (int k = 2; k < NK; ++k) {
      float cn = fmaf(twoc, ck, -ckm1);
      float sn = fmaf(twoc, sk, -skm1);
      cs[k - 1] += cn;
      ss[k - 1] += sn;
      ckm1 = ck; skm1 = sk; ck = cn; sk = sn;
    }
  }

  // ---- combine the two b-halves (lane L and L^32 share the same p col) ----
#pragma unroll
  for (int k = 0; k < NK - 1; ++k) {
    cs[k] += __shfl_xor(cs[k], 32, 64);
    ss[k] += __shfl_xor(ss[k], 32, 64);
  }

  // ---- planes (reuse tile LDS): cos[16][2 mt][64 p] @0, sin @2048 ----
  if (lane < 32) {
    int p = nt * 32 + (lane & 31);
#pragma unroll
    for (int k = 0; k < NK - 1; ++k) {
      smf[k * 128 + mt * 64 + p]        = cs[k];
      smf[2048 + k * 128 + mt * 64 + p] = ss[k];
    }
  }
  __syncthreads();

  // ---- per-(k,p) error + weight dot ----
  float part = 0.f;
#pragma unroll
  for (int r = 0; r < 4; ++r) {
    int e  = tid + r * 256;                      // 0..1023
    int k1 = e >> 6;
    int pl = e & 63;
    float C = smf[k1 * 128 + pl] + smf[k1 * 128 + 64 + pl];
    float S = smf[2048 + k1 * 128 + pl] + smf[2048 + k1 * 128 + 64 + pl];
    float cm  = C * (1.f / 64.f);
    float sm_ = S * (1.f / 64.f);
    float tk  = (float)(k1 + 1) * DT;
    float phi = __expf(-0.5f * tk * tk);
    float wk  = ((k1 == NK - 2) ? DT : 2.f * DT) * phi;   // k=16 endpoint
    float dc  = cm - phi;
    part = fmaf(wk, fmaf(dc, dc, sm_ * sm_), part);
  }
  part *= (1.f / 512.f);                         // * B / (T*P)

  // ---- block reduce -> one atomic per block ----
#pragma unroll
  for (int off = 32; off > 0; off >>= 1)
    part += __shfl_down(part, off, 64);
  __syncthreads();                               // done reading planes
  if (lane == 0) smf[4096 + wv] = part;          // 4096..4099 free (planes end at 4095)
  __syncthreads();
  if (tid == 0)
    atomicAdd(out, smf[4096] + smf[4097] + smf[4098] + smf[4099]);
}

// ---------------------------------------------------------------------------
extern "C" void kernel_launch(void* const* d_in, const int* in_sizes, int n_in,
                              void* d_out, int out_size, void* d_ws, size_t ws_size,
                              hipStream_t stream) {
  const float* proj = (const float*)d_in[0];     // (32,64,256) fp32
  const float* A    = (const float*)d_in[1];     // (256,1024) fp32
  float* out        = (float*)d_out;             // 1 fp32 scalar

  hipMemsetAsync(out, 0, sizeof(float), stream); // d_out poisoned each call
  sig_fused_kernel<<<dim3(16, 32), dim3(256), 0, stream>>>(proj, A, out);
}